// Round 1
// baseline (230.492 us; speedup 1.0000x reference)
//
#include <hip/hip_runtime.h>

// FeedForwardQuantum: out[r,e] = relu( (cos(x[r,:16])*cos(theta)) @ W1^T + b1 ) @ W2^T + b2
// r = b*4096+s, 65536 rows. E=512 F=64 Q=16. fp32 in/out, bf16 MFMA inner GEMM.
//
// Round-3 restructure: write-bound op (134 MB out vs 4 MB useful reads).
// Previous kernel had 16 syncthreads/block (each drains vmcnt -> stores never
// stream) and 4 B scalar stores. This version:
//   * 2 barriers per block total (z ready, h ready), then one uninterrupted
//     MFMA+store stream.
//   * operand-swapped MFMA: A = W2 (m=e), B = h^T (n=r). Fragment register
//     contents identical to the round-2-probe-validated ones, only the
//     intrinsic argument order changes. C layout (col=lane&15 = r,
//     row=quad*4+reg = e) now gives each lane 4 CONSECUTIVE e -> float4 store.
//   * b2 folded into MFMA C-init; W1 in registers; cos(theta) per-thread.
// Block = 256 thr (4 waves), owns 128 rows; wave w owns e in [w*128, w*128+128).

#define EMBED 512
#define FFN   64
#define RPB   128
#define NBLOCKS 512          // 65536 / 128

typedef __attribute__((ext_vector_type(8))) short short8;   // 8 x bf16
typedef __attribute__((ext_vector_type(4))) short short4_t; // 8 B
typedef __attribute__((ext_vector_type(4))) float floatx4;  // mfma acc

__device__ __forceinline__ short f2bf(float f) {
    union { float f; unsigned u; } v; v.f = f;
    unsigned u = v.u;
    return (short)((u + 0x7fffu + ((u >> 16) & 1u)) >> 16);   // RNE
}

__global__ __launch_bounds__(256, 2)
void ffq_kernel(const float* __restrict__ x,
                const float* __restrict__ theta,
                const float* __restrict__ W1,
                const float* __restrict__ b1,
                const float* __restrict__ W2,
                const float* __restrict__ b2,
                float* __restrict__ out)           // fp32 output
{
    __shared__ __align__(16) float z_s[RPB][20];   // stride 80 B: 2-way bank alias only
    __shared__ __align__(16) short h_s[RPB][72];   // stride 144 B: 2-way bank alias only

    const int t    = threadIdx.x;
    const int lane = t & 63;
    const int w    = t >> 6;        // wave id 0..3
    const int quad = lane >> 4;     // 0..3
    const int l16  = lane & 15;
    const int rowBase = blockIdx.x * RPB;

    // ---- issue x loads FIRST (the only HBM-latency reads) ----
    // thread covers rows r0 and r0+64, float4-column c (64 B/row = 1 cache line)
    const int c  = t & 3;
    const int r0 = t >> 2;          // 0..63
    const float4 xv0 = *(const float4*)(x + (size_t)(rowBase + r0)      * EMBED + c * 4);
    const float4 xv1 = *(const float4*)(x + (size_t)(rowBase + r0 + 64) * EMBED + c * 4);

    // cos(theta) for this thread's 4 columns (no LDS, no barrier needed)
    const float4 th = *(const float4*)(theta + c * 4);
    const float ctx = cosf(th.x), cty = cosf(th.y), ctz = cosf(th.z), ctw = cosf(th.w);

    // ---- W2 A-fragments (bf16, registers): A[m=e(l16)][k=f(quad*8+j)] ----
    short8 afrag[8][2];
#pragma unroll
    for (int tile = 0; tile < 8; ++tile) {
        const int e = w * 128 + tile * 16 + l16;
#pragma unroll
        for (int s = 0; s < 2; ++s) {
            const int f0 = s * 32 + quad * 8;
            const float4* p = (const float4*)(W2 + (size_t)e * FFN + f0);
            const float4 lo = p[0], hi = p[1];
            short8 fr;
            fr[0] = f2bf(lo.x); fr[1] = f2bf(lo.y); fr[2] = f2bf(lo.z); fr[3] = f2bf(lo.w);
            fr[4] = f2bf(hi.x); fr[5] = f2bf(hi.y); fr[6] = f2bf(hi.z); fr[7] = f2bf(hi.w);
            afrag[tile][s] = fr;
        }
    }

    // ---- b2 as MFMA C-init: lane's 4 regs = e = w*128 + tile*16 + quad*4 + reg ----
    floatx4 b2f[8];
#pragma unroll
    for (int tile = 0; tile < 8; ++tile) {
        const float4 v = *(const float4*)(b2 + w * 128 + tile * 16 + quad * 4);
        floatx4 a; a[0] = v.x; a[1] = v.y; a[2] = v.z; a[3] = v.w;
        b2f[tile] = a;
    }

    // ---- W1 rows in registers for the h phase (thread g computes h[.][4g..4g+4)) ----
    const int g = t >> 4;           // 0..15
    float4 w1r[4][4];
#pragma unroll
    for (int i = 0; i < 4; ++i)
#pragma unroll
        for (int kq = 0; kq < 4; ++kq)
            w1r[i][kq] = *(const float4*)(W1 + (size_t)(g * 4 + i) * 16 + kq * 4);
    const float4 b1v = *(const float4*)(b1 + g * 4);
    float b1a[4] = {b1v.x, b1v.y, b1v.z, b1v.w};

    // ---- z phase: all 128 rows at once ----
    {
        float4 z0, z1;
        z0.x = cosf(xv0.x) * ctx; z0.y = cosf(xv0.y) * cty;
        z0.z = cosf(xv0.z) * ctz; z0.w = cosf(xv0.w) * ctw;
        z1.x = cosf(xv1.x) * ctx; z1.y = cosf(xv1.y) * cty;
        z1.z = cosf(xv1.z) * ctz; z1.w = cosf(xv1.w) * ctw;
        *(float4*)&z_s[r0][c * 4]      = z0;
        *(float4*)&z_s[r0 + 64][c * 4] = z1;
    }
    __syncthreads();

    // ---- h phase: all 128 rows; thread (hr, g) does h[rg*16+hr][4g..4g+4) ----
    const int hr = t & 15;
#pragma unroll
    for (int rg = 0; rg < 8; ++rg) {
        const int r = rg * 16 + hr;
        const float4 zr0 = *(const float4*)&z_s[r][0];
        const float4 zr1 = *(const float4*)&z_s[r][4];
        const float4 zr2 = *(const float4*)&z_s[r][8];
        const float4 zr3 = *(const float4*)&z_s[r][12];
        short4_t hv;
#pragma unroll
        for (int i = 0; i < 4; ++i) {
            float s0 = b1a[i];
            s0 += zr0.x * w1r[i][0].x + zr0.y * w1r[i][0].y + zr0.z * w1r[i][0].z + zr0.w * w1r[i][0].w;
            s0 += zr1.x * w1r[i][1].x + zr1.y * w1r[i][1].y + zr1.z * w1r[i][1].z + zr1.w * w1r[i][1].w;
            s0 += zr2.x * w1r[i][2].x + zr2.y * w1r[i][2].y + zr2.z * w1r[i][2].z + zr2.w * w1r[i][2].w;
            s0 += zr3.x * w1r[i][3].x + zr3.y * w1r[i][3].y + zr3.z * w1r[i][3].z + zr3.w * w1r[i][3].w;
            hv[i] = f2bf(fmaxf(s0, 0.0f));      // relu then bf16
        }
        *(short4_t*)&h_s[r][g * 4] = hv;
    }
    __syncthreads();

    // ---- MFMA + streamed float4 stores, no further barriers ----
    // B-frag (h): B[k=quad*8+j][n=l16] = h[r=l16][f] -> same LDS read as before.
    // D[m=e][n=r]: lane stores out[rowBase+rg*16+l16][w*128+tile*16+quad*4 .. +3]
#pragma unroll 2
    for (int rg = 0; rg < 8; ++rg) {
        const short8 hb0 = *(const short8*)&h_s[rg * 16 + l16][quad * 8];
        const short8 hb1 = *(const short8*)&h_s[rg * 16 + l16][32 + quad * 8];
        float* op = out + (size_t)(rowBase + rg * 16 + l16) * EMBED + w * 128 + quad * 4;
#pragma unroll
        for (int tile = 0; tile < 8; ++tile) {
            floatx4 acc = b2f[tile];
            acc = __builtin_amdgcn_mfma_f32_16x16x32_bf16(afrag[tile][0], hb0, acc, 0, 0, 0);
            acc = __builtin_amdgcn_mfma_f32_16x16x32_bf16(afrag[tile][1], hb1, acc, 0, 0, 0);
            *(floatx4*)(op + tile * 16) = acc;   // global_store_dwordx4
        }
    }
}

extern "C" void kernel_launch(void* const* d_in, const int* in_sizes, int n_in,
                              void* d_out, int out_size, void* d_ws, size_t ws_size,
                              hipStream_t stream) {
    const float* x     = (const float*)d_in[0];
    const float* theta = (const float*)d_in[1];
    const float* W1    = (const float*)d_in[2];
    const float* b1    = (const float*)d_in[3];
    const float* W2    = (const float*)d_in[4];
    const float* b2    = (const float*)d_in[5];
    float* out = (float*)d_out;

    ffq_kernel<<<NBLOCKS, 256, 0, stream>>>(x, theta, W1, b1, W2, b2, out);
}